// Round 9
// baseline (71.382 us; speedup 1.0000x reference)
//
#include <hip/hip_runtime.h>
#include <hip/hip_bf16.h>

typedef float f32x4 __attribute__((ext_vector_type(4)));
typedef short bf16x8 __attribute__((ext_vector_type(8)));

#define LRELU_SLOPE 0.2f
#define SQRT2F 1.4142135623730951f
#define MODSCALE 0.044194173824159216f  // 512^-0.5

#define GLL(SRC, DST)                                                       \
  __builtin_amdgcn_global_load_lds(                                         \
      (const __attribute__((address_space(1))) unsigned int*)(SRC),         \
      (__attribute__((address_space(3))) unsigned int*)(DST), 16, 0, 0)

// ---------- kernel 1: fused prep: wprep (blocks 0..1023) + style (1024..1151)
//            + xsp border zero (1152..1415) ----------
__global__ __launch_bounds__(256) void prep_kernel(const float* __restrict__ w,
                                                   const float* __restrict__ y,
                                                   const float* __restrict__ mw,
                                                   const float* __restrict__ bias,
                                                   __hip_bfloat16* __restrict__ wt,
                                                   float* __restrict__ wsq,
                                                   float* __restrict__ s,
                                                   __hip_bfloat16* __restrict__ xsp) {
  const int bid = blockIdx.x;
  const int tid = threadIdx.x;
  if (bid < 1024) {  // ---- weight prep: wt[t][co][ci] bf16 + wsq[co][ci] ----
    int idx = bid * 256 + tid;  // co*512+ci
    const float* p = w + (size_t)idx * 9;
    float v[9];
    float sq = 0.f;
#pragma unroll
    for (int t = 0; t < 9; ++t) {
      v[t] = p[t];
      sq += v[t] * v[t];
    }
    wsq[idx] = sq;
#pragma unroll
    for (int t = 0; t < 9; ++t) wt[t * 262144 + idx] = __float2bfloat16(v[t]);
  } else if (bid < 1152) {  // ---- style: one ci per wave ----
    int l = tid & 63;
    int ci = (bid - 1024) * 4 + (tid >> 6);
    const float4* mwr = reinterpret_cast<const float4*>(mw + ci * 512);
    float4 m0 = mwr[2 * l], m1 = mwr[2 * l + 1];
    float acc[8];
#pragma unroll
    for (int b = 0; b < 8; ++b) {
      const float4* yr = reinterpret_cast<const float4*>(y + b * 512);
      float4 y0 = yr[2 * l], y1 = yr[2 * l + 1];
      acc[b] = m0.x * y0.x + m0.y * y0.y + m0.z * y0.z + m0.w * y0.w +
               m1.x * y1.x + m1.y * y1.y + m1.z * y1.z + m1.w * y1.w;
    }
#pragma unroll
    for (int off = 32; off > 0; off >>= 1) {
#pragma unroll
      for (int b = 0; b < 8; ++b) acc[b] += __shfl_xor(acc[b], off, 64);
    }
    if (l < 8) {
      float v = acc[l] * MODSCALE + bias[ci];
      v = v > 0.f ? v : LRELU_SLOPE * v;
      s[l * 512 + ci] = v * SQRT2F;
    }
  } else {  // ---- zero the 1-px halo border of xsp (interior written by xs) ----
    int i = (bid - 1152) * 256 + tid;  // 264*256 = 67584 = 8 * 132 * 64
    int b = i / 8448;
    int r = i - b * 8448;
    int pos = r >> 6;
    int cj = (r & 63) << 3;
    int hr, hc;
    if (pos < 34) { hr = 0; hc = pos; }
    else if (pos < 68) { hr = 33; hc = pos - 34; }
    else if (pos < 100) { hr = pos - 67; hc = 0; }
    else { hr = pos - 99; hc = 33; }
    unsigned off = (unsigned)((b * 34 + hr) * 34 + hc) * 512 + cj;
    int4 z = {0, 0, 0, 0};
    *reinterpret_cast<int4*>(xsp + off) = z;
  }
}

// ---------- kernel 2: fused xs (blocks 0..2047) + demod (2048..2175) ----------
__global__ __launch_bounds__(256) void xsdem_kernel(const float* __restrict__ x,
                                                    const float* __restrict__ s,
                                                    const float* __restrict__ wsq,
                                                    __hip_bfloat16* __restrict__ xsp,
                                                    float* __restrict__ d) {
  const int bid = blockIdx.x;
  const int tid = threadIdx.x;
  if (bid < 2048) {  // ---- xs: NCHW f32 -> padded NHWC bf16, x * s ----
    int cc = bid & 7;
    int h = (bid >> 3) & 31;
    int b = bid >> 8;
    __shared__ __hip_bfloat16 tile[32][72];
    int cil = tid >> 2;
    int w0 = (tid & 3) * 8;
    int ci = cc * 64 + cil;
    const float* xp = x + (((size_t)(b * 512 + ci) * 32 + h) << 5) + w0;
    float sv = s[b * 512 + ci];
    float4 a0 = *reinterpret_cast<const float4*>(xp);
    float4 a1 = *reinterpret_cast<const float4*>(xp + 4);
    tile[w0 + 0][cil] = __float2bfloat16(a0.x * sv);
    tile[w0 + 1][cil] = __float2bfloat16(a0.y * sv);
    tile[w0 + 2][cil] = __float2bfloat16(a0.z * sv);
    tile[w0 + 3][cil] = __float2bfloat16(a0.w * sv);
    tile[w0 + 4][cil] = __float2bfloat16(a1.x * sv);
    tile[w0 + 5][cil] = __float2bfloat16(a1.y * sv);
    tile[w0 + 6][cil] = __float2bfloat16(a1.z * sv);
    tile[w0 + 7][cil] = __float2bfloat16(a1.w * sv);
    __syncthreads();
    int wloc = tid >> 3;
    int cj = (tid & 7) * 8;
    int4 v = *reinterpret_cast<const int4*>(&tile[wloc][cj]);
    unsigned off = (unsigned)((b * 34 + h + 1) * 34 + (wloc + 1)) * 512 + cc * 64 + cj;
    *reinterpret_cast<int4*>(xsp + off) = v;
  } else {  // ---- demod: one co per wave ----
    int l = tid & 63;
    int co = (bid - 2048) * 4 + (tid >> 6);
    const float4* qr = reinterpret_cast<const float4*>(wsq + co * 512);
    float4 q0 = qr[2 * l], q1 = qr[2 * l + 1];
    float acc[8];
#pragma unroll
    for (int b = 0; b < 8; ++b) {
      const float4* sr = reinterpret_cast<const float4*>(s + b * 512);
      float4 s0 = sr[2 * l], s1 = sr[2 * l + 1];
      acc[b] = q0.x * s0.x * s0.x + q0.y * s0.y * s0.y + q0.z * s0.z * s0.z +
               q0.w * s0.w * s0.w + q1.x * s1.x * s1.x + q1.y * s1.y * s1.y +
               q1.z * s1.z * s1.z + q1.w * s1.w * s1.w;
    }
#pragma unroll
    for (int off = 32; off > 0; off >>= 1) {
#pragma unroll
      for (int b = 0; b < 8; ++b) acc[b] += __shfl_xor(acc[b], off, 64);
    }
    if (l < 8) d[l * 512 + co] = rsqrtf(acc[l] + 1e-8f);
  }
}

// ---------- kernel 3: conv — halo implicit GEMM, 8 waves, K-split ----------
// B: 4 LDS slots, distance-3-phase prefetch; A: dbuf, staged 5-9 phases ahead.
// Per phase: exact counted vmcnt -> barrier -> stages -> 8 ds_read -> 16 MFMA.
// Steady N table {4,5,6,7,7,6,5,4,4}; drain {4,4,4,4,4,4,4,2,0}.
__global__ __launch_bounds__(512, 2) void conv_kernel(const __hip_bfloat16* __restrict__ xsp,
                                                      const __hip_bfloat16* __restrict__ wt,
                                                      const float* __restrict__ dmod,
                                                      float* __restrict__ out) {
  __shared__ __hip_bfloat16 As_[2][224 * 64];  // 2 x 28 KB (204 halo rows used)
  __shared__ __hip_bfloat16 Bs_[4][128 * 64];  // 4 x 16 KB
  const int bid = blockIdx.x;  // 256 blocks
  const int xcd = bid & 7, slot0 = bid >> 3;   // XCD-aware remap
  const int bm = xcd * 8 + (slot0 >> 2);
  const int bn = slot0 & 3;
  const int tid = threadIdx.x;
  const int wv = tid >> 6;
  const int l = tid & 63;
  const int kg = wv >> 2;          // K-group (owns 32 of 64 ci per chunk)
  const int wr = (wv >> 1) & 1, wc = wv & 1;
  const int bb = bm >> 3;          // batch
  const int h0 = (bm & 7) << 2;    // first output image row of tile

  const int swz = (((l & 7) ^ (l >> 3)) << 3);  // staging pre-swizzle (row&7 == l>>3)
  unsigned boff[2];
#pragma unroll
  for (int j = 0; j < 2; ++j) {
    int row = ((j * 8 + wv) << 3) + (l >> 3);
    boff[j] = (unsigned)((bn << 7) + row) * 512 + swz;
  }
  unsigned ahoff[4];
  int adst[4];
#pragma unroll
  for (int j = 0; j < 4; ++j) {
    int rb = j < 3 ? j * 64 + wv * 8 : 192 + (wv & 3) * 8;  // j=3: wave pairs duplicate
    int r = rb + (l >> 3);
    int rc = r > 203 ? 203 : r;
    int hr = rc / 34, hc = rc - hr * 34;
    ahoff[j] = (unsigned)((bb * 34 + h0 + hr) * 34 + hc) * 512 + (((l & 7) ^ (r & 7)) << 3);
    adst[j] = rb;
  }
  int pb[4];
#pragma unroll
  for (int m = 0; m < 4; ++m)
    pb[m] = ((wr << 1) + (m >> 1)) * 34 + ((m & 1) << 4) + (l & 15);

  f32x4 acc[4][4];
#pragma unroll
  for (int n = 0; n < 4; ++n)
#pragma unroll
    for (int m = 0; m < 4; ++m) acc[n][m] = (f32x4)0.f;

  auto stageB = [&](int sl, int t, int k0c) {
    const __hip_bfloat16* src = wt + t * 262144 + k0c * 64;
#pragma unroll
    for (int j = 0; j < 2; ++j)
      GLL(src + boff[j], &Bs_[sl][(j * 8 + wv) << 9]);
  };
  auto stageA1 = [&](int ab, int j, int kn) {
    GLL(xsp + ahoff[j] + kn * 64, &As_[ab][adst[j] << 6]);
  };
  auto phase = [&](int ab, int sl, int dh, int dw) {
    const int cb = (kg << 2) + (l >> 4);
    bf16x8 af[4], bfr[4];
#pragma unroll
    for (int m = 0; m < 4; ++m) {
      int p = pb[m] + dh * 34 + dw;
      af[m] = *reinterpret_cast<const bf16x8*>(&As_[ab][p * 64 + ((cb ^ (p & 7)) << 3)]);
    }
#pragma unroll
    for (int n = 0; n < 4; ++n) {
      int row = (wc << 6) + (n << 4) + (l & 15);
      bfr[n] = *reinterpret_cast<const bf16x8*>(&Bs_[sl][row * 64 + ((cb ^ (l & 7)) << 3)]);
    }
    __builtin_amdgcn_s_setprio(1);
#pragma unroll
    for (int n = 0; n < 4; ++n)
#pragma unroll
      for (int m = 0; m < 4; ++m)
        acc[n][m] = __builtin_amdgcn_mfma_f32_16x16x32_bf16(bfr[n], af[m], acc[n][m], 0, 0, 0);
    __builtin_amdgcn_s_setprio(0);
  };

#define SB0 __builtin_amdgcn_sched_barrier(0)
#define WB(N)                                               \
  asm volatile("s_waitcnt vmcnt(" #N ")" ::: "memory");     \
  __builtin_amdgcn_s_barrier();                             \
  SB0

  // prologue queue per wave: [A0,A1,A2,A3, B0x2, B1x2, B2x2]
#pragma unroll
  for (int j = 0; j < 4; ++j) stageA1(0, j, 0);
  SB0;
  stageB(0, 0, 0);
  stageB(1, 1, 0);
  stageB(2, 2, 0);

#pragma unroll 1
  for (int k0 = 0; k0 < 7; ++k0) {  // steady chunks
    const int a = k0 & 1, an = a ^ 1, kn = k0 + 1;
    WB(4); stageB((k0 + 3) & 3, 3, k0); stageA1(an, 0, kn); SB0; phase(a, (k0 + 0) & 3, 0, 0);
    WB(5); stageB((k0 + 4) & 3, 4, k0); stageA1(an, 1, kn); SB0; phase(a, (k0 + 1) & 3, 0, 1);
    WB(6); stageB((k0 + 5) & 3, 5, k0); stageA1(an, 2, kn); SB0; phase(a, (k0 + 2) & 3, 0, 2);
    WB(7); stageB((k0 + 6) & 3, 6, k0); stageA1(an, 3, kn); SB0; phase(a, (k0 + 3) & 3, 1, 0);
    WB(7); stageB((k0 + 7) & 3, 7, k0); SB0; phase(a, (k0 + 4) & 3, 1, 1);
    WB(6); stageB((k0 + 8) & 3, 8, k0); SB0; phase(a, (k0 + 5) & 3, 1, 2);
    WB(5); stageB((k0 + 9) & 3, 0, kn); SB0; phase(a, (k0 + 6) & 3, 2, 0);
    WB(4); stageB((k0 + 10) & 3, 1, kn); SB0; phase(a, (k0 + 7) & 3, 2, 1);
    WB(4); stageB((k0 + 11) & 3, 2, kn); SB0; phase(a, (k0 + 8) & 3, 2, 2);
  }
  {  // drain chunk k0 = 7 (no A stages, no next-chunk B)
    WB(4); stageB((7 + 3) & 3, 3, 7); SB0; phase(1, (7 + 0) & 3, 0, 0);
    WB(4); stageB((7 + 4) & 3, 4, 7); SB0; phase(1, (7 + 1) & 3, 0, 1);
    WB(4); stageB((7 + 5) & 3, 5, 7); SB0; phase(1, (7 + 2) & 3, 0, 2);
    WB(4); stageB((7 + 6) & 3, 6, 7); SB0; phase(1, (7 + 3) & 3, 1, 0);
    WB(4); stageB((7 + 7) & 3, 7, 7); SB0; phase(1, (7 + 4) & 3, 1, 1);
    WB(4); stageB((7 + 8) & 3, 8, 7); SB0; phase(1, (7 + 5) & 3, 1, 2);
    WB(4); SB0; phase(1, (7 + 6) & 3, 2, 0);
    WB(2); SB0; phase(1, (7 + 7) & 3, 2, 1);
    WB(0); SB0; phase(1, (7 + 8) & 3, 2, 2);
  }
#undef WB
#undef SB0

  // ---- cross-kg reduction via LDS (over Bs_, exactly 64 KB) ----
  float* red = reinterpret_cast<float*>(&Bs_[0][0]);
  __syncthreads();
  if (kg == 1) {
#pragma unroll
    for (int n = 0; n < 4; ++n)
#pragma unroll
      for (int m = 0; m < 4; ++m)
        *reinterpret_cast<f32x4*>(red + (n * 4 + m) * 1024 + (wv & 3) * 256 + l * 4) =
            acc[n][m];
  }
  __syncthreads();
  if (kg == 0) {
    const int pixbase = ((bm & 7) << 7) + (wr << 6) + (l & 15);
    const int cob = (bn << 7) + (wc << 6) + ((l >> 4) << 2);
    float* ob = out + ((size_t)bb << 19);
    const float* drow = dmod + bb * 512;
#pragma unroll
    for (int n = 0; n < 4; ++n) {
#pragma unroll
      for (int m = 0; m < 4; ++m)
        acc[n][m] += *reinterpret_cast<const f32x4*>(red + (n * 4 + m) * 1024 + wv * 256 + l * 4);
#pragma unroll
      for (int jj = 0; jj < 4; ++jj) {
        const int co = cob + (n << 4) + jj;
        const float dv = drow[co];
        float* orow = ob + ((unsigned)co << 10) + pixbase;
#pragma unroll
        for (int m = 0; m < 4; ++m) orow[m << 4] = acc[n][m][jj] * dv;
      }
    }
  }
}

extern "C" void kernel_launch(void* const* d_in, const int* in_sizes, int n_in,
                              void* d_out, int out_size, void* d_ws, size_t ws_size,
                              hipStream_t stream) {
  (void)in_sizes; (void)n_in; (void)out_size; (void)ws_size;
  const float* x = (const float*)d_in[0];       // [8,512,32,32]
  const float* y = (const float*)d_in[1];       // [8,512]
  const float* w = (const float*)d_in[2];       // [512,512,3,3]
  const float* mw = (const float*)d_in[3];      // [512,512]
  const float* bias = (const float*)d_in[4];    // [512]
  float* out = (float*)d_out;                   // [8,512,32,32]

  char* ws = (char*)d_ws;
  float* s = (float*)(ws + 0);                  // 16 KB
  float* dmod = (float*)(ws + 16384);           // 16 KB
  float* wsq = (float*)(ws + 32768);            // 1 MB
  __hip_bfloat16* wt = (__hip_bfloat16*)(ws + 1081344);    // 9*512*512*2 = 4.5 MB
  __hip_bfloat16* xsp = (__hip_bfloat16*)(ws + 5799936);   // 8*34*34*512*2 = 9.03 MB

  prep_kernel<<<1416, 256, 0, stream>>>(w, y, mw, bias, wt, wsq, s, xsp);
  xsdem_kernel<<<2176, 256, 0, stream>>>(x, s, wsq, xsp, dmod);
  conv_kernel<<<256, 512, 0, stream>>>(xsp, wt, dmod, out);
}

// Round 10
// 64.329 us; speedup vs baseline: 1.1096x; 1.1096x over previous
//
#include <hip/hip_runtime.h>
#include <hip/hip_bf16.h>

typedef float f32x4 __attribute__((ext_vector_type(4)));
typedef short bf16x8 __attribute__((ext_vector_type(8)));

#define LRELU_SLOPE 0.2f
#define SQRT2F 1.4142135623730951f
#define MODSCALE 0.044194173824159216f  // 512^-0.5

#define GLL(SRC, DST)                                                       \
  __builtin_amdgcn_global_load_lds(                                         \
      (const __attribute__((address_space(1))) unsigned int*)(SRC),         \
      (__attribute__((address_space(3))) unsigned int*)(DST), 16, 0, 0)

// ---------- kernel 1: fused prep: wprep (blocks 0..1023) + style (1024..1151)
//            + xsp border zero (1152..1415) ----------
__global__ __launch_bounds__(256) void prep_kernel(const float* __restrict__ w,
                                                   const float* __restrict__ y,
                                                   const float* __restrict__ mw,
                                                   const float* __restrict__ bias,
                                                   __hip_bfloat16* __restrict__ wt,
                                                   float* __restrict__ wsq,
                                                   float* __restrict__ s,
                                                   __hip_bfloat16* __restrict__ xsp) {
  const int bid = blockIdx.x;
  const int tid = threadIdx.x;
  if (bid < 1024) {  // ---- weight prep: wt[t][co][ci] bf16 + wsq[co][ci] ----
    int idx = bid * 256 + tid;  // co*512+ci
    const float* p = w + (size_t)idx * 9;
    float v[9];
    float sq = 0.f;
#pragma unroll
    for (int t = 0; t < 9; ++t) {
      v[t] = p[t];
      sq += v[t] * v[t];
    }
    wsq[idx] = sq;
#pragma unroll
    for (int t = 0; t < 9; ++t) wt[t * 262144 + idx] = __float2bfloat16(v[t]);
  } else if (bid < 1152) {  // ---- style: one ci per wave ----
    int l = tid & 63;
    int ci = (bid - 1024) * 4 + (tid >> 6);
    const float4* mwr = reinterpret_cast<const float4*>(mw + ci * 512);
    float4 m0 = mwr[2 * l], m1 = mwr[2 * l + 1];
    float acc[8];
#pragma unroll
    for (int b = 0; b < 8; ++b) {
      const float4* yr = reinterpret_cast<const float4*>(y + b * 512);
      float4 y0 = yr[2 * l], y1 = yr[2 * l + 1];
      acc[b] = m0.x * y0.x + m0.y * y0.y + m0.z * y0.z + m0.w * y0.w +
               m1.x * y1.x + m1.y * y1.y + m1.z * y1.z + m1.w * y1.w;
    }
#pragma unroll
    for (int off = 32; off > 0; off >>= 1) {
#pragma unroll
      for (int b = 0; b < 8; ++b) acc[b] += __shfl_xor(acc[b], off, 64);
    }
    if (l < 8) {
      float v = acc[l] * MODSCALE + bias[ci];
      v = v > 0.f ? v : LRELU_SLOPE * v;
      s[l * 512 + ci] = v * SQRT2F;
    }
  } else {  // ---- zero the 1-px halo border of xsp (interior written by xs) ----
    int i = (bid - 1152) * 256 + tid;  // 264*256 = 67584 = 8 * 132 * 64
    int b = i / 8448;
    int r = i - b * 8448;
    int pos = r >> 6;
    int cj = (r & 63) << 3;
    int hr, hc;
    if (pos < 34) { hr = 0; hc = pos; }
    else if (pos < 68) { hr = 33; hc = pos - 34; }
    else if (pos < 100) { hr = pos - 67; hc = 0; }
    else { hr = pos - 99; hc = 33; }
    unsigned off = (unsigned)((b * 34 + hr) * 34 + hc) * 512 + cj;
    int4 z = {0, 0, 0, 0};
    *reinterpret_cast<int4*>(xsp + off) = z;
  }
}

// ---------- kernel 2: fused xs (blocks 0..2047) + demod (2048..2175) ----------
__global__ __launch_bounds__(256) void xsdem_kernel(const float* __restrict__ x,
                                                    const float* __restrict__ s,
                                                    const float* __restrict__ wsq,
                                                    __hip_bfloat16* __restrict__ xsp,
                                                    float* __restrict__ d) {
  const int bid = blockIdx.x;
  const int tid = threadIdx.x;
  if (bid < 2048) {  // ---- xs: NCHW f32 -> padded NHWC bf16, x * s ----
    int cc = bid & 7;
    int h = (bid >> 3) & 31;
    int b = bid >> 8;
    __shared__ __hip_bfloat16 tile[32][72];
    int cil = tid >> 2;
    int w0 = (tid & 3) * 8;
    int ci = cc * 64 + cil;
    const float* xp = x + (((size_t)(b * 512 + ci) * 32 + h) << 5) + w0;
    float sv = s[b * 512 + ci];
    float4 a0 = *reinterpret_cast<const float4*>(xp);
    float4 a1 = *reinterpret_cast<const float4*>(xp + 4);
    tile[w0 + 0][cil] = __float2bfloat16(a0.x * sv);
    tile[w0 + 1][cil] = __float2bfloat16(a0.y * sv);
    tile[w0 + 2][cil] = __float2bfloat16(a0.z * sv);
    tile[w0 + 3][cil] = __float2bfloat16(a0.w * sv);
    tile[w0 + 4][cil] = __float2bfloat16(a1.x * sv);
    tile[w0 + 5][cil] = __float2bfloat16(a1.y * sv);
    tile[w0 + 6][cil] = __float2bfloat16(a1.z * sv);
    tile[w0 + 7][cil] = __float2bfloat16(a1.w * sv);
    __syncthreads();
    int wloc = tid >> 3;
    int cj = (tid & 7) * 8;
    int4 v = *reinterpret_cast<const int4*>(&tile[wloc][cj]);
    unsigned off = (unsigned)((b * 34 + h + 1) * 34 + (wloc + 1)) * 512 + cc * 64 + cj;
    *reinterpret_cast<int4*>(xsp + off) = v;
  } else {  // ---- demod: one co per wave ----
    int l = tid & 63;
    int co = (bid - 2048) * 4 + (tid >> 6);
    const float4* qr = reinterpret_cast<const float4*>(wsq + co * 512);
    float4 q0 = qr[2 * l], q1 = qr[2 * l + 1];
    float acc[8];
#pragma unroll
    for (int b = 0; b < 8; ++b) {
      const float4* sr = reinterpret_cast<const float4*>(s + b * 512);
      float4 s0 = sr[2 * l], s1 = sr[2 * l + 1];
      acc[b] = q0.x * s0.x * s0.x + q0.y * s0.y * s0.y + q0.z * s0.z * s0.z +
               q0.w * s0.w * s0.w + q1.x * s1.x * s1.x + q1.y * s1.y * s1.y +
               q1.z * s1.z * s1.z + q1.w * s1.w * s1.w;
    }
#pragma unroll
    for (int off = 32; off > 0; off >>= 1) {
#pragma unroll
      for (int b = 0; b < 8; ++b) acc[b] += __shfl_xor(acc[b], off, 64);
    }
    if (l < 8) d[l * 512 + co] = rsqrtf(acc[l] + 1e-8f);
  }
}

// ---------- kernel 3: conv — halo implicit GEMM, 8 waves, K-split,
//            register-pipelined fragments (read phase g+1 under MFMA of phase g) ----------
__global__ __launch_bounds__(512, 2) void conv_kernel(const __hip_bfloat16* __restrict__ xsp,
                                                      const __hip_bfloat16* __restrict__ wt,
                                                      const float* __restrict__ dmod,
                                                      float* __restrict__ out) {
  __shared__ __hip_bfloat16 As_[2][224 * 64];  // 2 x 28 KB (204 halo rows used)
  __shared__ __hip_bfloat16 Bs_[4][128 * 64];  // 4 x 16 KB
  const int bid = blockIdx.x;  // 256 blocks
  const int xcd = bid & 7, slot0 = bid >> 3;   // XCD-aware remap
  const int bm = xcd * 8 + (slot0 >> 2);
  const int bn = slot0 & 3;
  const int tid = threadIdx.x;
  const int wv = tid >> 6;
  const int l = tid & 63;
  const int kg = wv >> 2;          // K-group (owns 32 of 64 ci per chunk)
  const int wr = (wv >> 1) & 1, wc = wv & 1;
  const int bb = bm >> 3;          // batch
  const int h0 = (bm & 7) << 2;    // first output image row of tile

  const int swz = (((l & 7) ^ (l >> 3)) << 3);  // staging pre-swizzle (row&7 == l>>3)
  unsigned boff[2];
#pragma unroll
  for (int j = 0; j < 2; ++j) {
    int row = ((j * 8 + wv) << 3) + (l >> 3);
    boff[j] = (unsigned)((bn << 7) + row) * 512 + swz;
  }
  unsigned ahoff[4];
  int adst[4];
#pragma unroll
  for (int j = 0; j < 4; ++j) {
    int rb = j < 3 ? j * 64 + wv * 8 : 192 + (wv & 3) * 8;  // j=3: wave pairs duplicate
    int r = rb + (l >> 3);
    int rc = r > 203 ? 203 : r;
    int hr = rc / 34, hc = rc - hr * 34;
    ahoff[j] = (unsigned)((bb * 34 + h0 + hr) * 34 + hc) * 512 + (((l & 7) ^ (r & 7)) << 3);
    adst[j] = rb;
  }
  int pb[4];
#pragma unroll
  for (int m = 0; m < 4; ++m)
    pb[m] = ((wr << 1) + (m >> 1)) * 34 + ((m & 1) << 4) + (l & 15);

  f32x4 acc[4][4];
#pragma unroll
  for (int n = 0; n < 4; ++n)
#pragma unroll
    for (int m = 0; m < 4; ++m) acc[n][m] = (f32x4)0.f;

  bf16x8 fa[2][4], fb[2][4];  // double-banked fragments (static index after unroll)

  auto stageB = [&](int sl, int t, int k0c) {
    const __hip_bfloat16* src = wt + t * 262144 + k0c * 64;
#pragma unroll
    for (int j = 0; j < 2; ++j)
      GLL(src + boff[j], &Bs_[sl][(j * 8 + wv) << 9]);
  };
  auto stageA1 = [&](int ab, int j, int kn) {
    GLL(xsp + ahoff[j] + kn * 64, &As_[ab][adst[j] << 6]);
  };
  auto readfrag = [&](int bk, int ab, int sl, int dh, int dw) {
    const int cb = (kg << 2) + (l >> 4);
#pragma unroll
    for (int m = 0; m < 4; ++m) {
      int p = pb[m] + dh * 34 + dw;
      fa[bk][m] = *reinterpret_cast<const bf16x8*>(&As_[ab][p * 64 + ((cb ^ (p & 7)) << 3)]);
    }
#pragma unroll
    for (int n = 0; n < 4; ++n) {
      int row = (wc << 6) + (n << 4) + (l & 15);
      fb[bk][n] = *reinterpret_cast<const bf16x8*>(&Bs_[sl][row * 64 + ((cb ^ (l & 7)) << 3)]);
    }
  };
  auto mfmacl = [&](int bk) {
    __builtin_amdgcn_s_setprio(1);
#pragma unroll
    for (int n = 0; n < 4; ++n)
#pragma unroll
      for (int m = 0; m < 4; ++m)
        acc[n][m] = __builtin_amdgcn_mfma_f32_16x16x32_bf16(fb[bk][n], fa[bk][m], acc[n][m], 0, 0, 0);
    __builtin_amdgcn_s_setprio(0);
  };
  auto waitbar = [&](int n) {
    if (n == 0) asm volatile("s_waitcnt vmcnt(0)" ::: "memory");
    else if (n == 2) asm volatile("s_waitcnt vmcnt(2)" ::: "memory");
    else if (n == 3) asm volatile("s_waitcnt vmcnt(3)" ::: "memory");
    else asm volatile("s_waitcnt vmcnt(4)" ::: "memory");
    __builtin_amdgcn_s_barrier();
    __builtin_amdgcn_sched_barrier(0);
  };
  // body g = 9*cbase + uC (cbase even). Stage B for phase g+3; A piece t (t<4) for chunk
  // c+1; read fragments for phase g+1 into bank^1; MFMA phase g on bank = uC&1.
  auto body = [&](int uC, int cbase, bool stA) {
    const int t = uC % 9;
    const int bank = uC & 1;
    const int N = ((uC + 8) % 9 < 4) ? 3 : 2;  // = loads issued in body g-1
    waitbar(N);
    const int t3 = (uC + 3) % 9;
    stageB((cbase + uC + 3) & 3, t3, cbase + (uC + 3) / 9);
    if (stA && t < 4) stageA1(((uC / 9) & 1) ^ 1, t, cbase + uC / 9 + 1);
    __builtin_amdgcn_sched_barrier(0);
    const int t1 = (uC + 1) % 9;
    readfrag(bank ^ 1, ((uC + 1) / 9) & 1, (cbase + uC + 1) & 3, t1 / 3, t1 % 3);
    __builtin_amdgcn_sched_barrier(0);
    mfmacl(bank);
  };
  auto body7 = [&](int uC) {  // chunk 7 drain: g = 63+uC, bank = (uC+1)&1
    const int bank = (uC + 1) & 1;
    waitbar(uC >= 7 ? 0 : 2);
    if (uC < 6) stageB((uC + 2) & 3, uC + 3, 7);
    __builtin_amdgcn_sched_barrier(0);
    if (uC < 8) readfrag(bank ^ 1, 1, uC & 3, (uC + 1) / 3, (uC + 1) % 3);
    __builtin_amdgcn_sched_barrier(0);
    mfmacl(bank);
  };

  // prologue: A chunk 0 (4 pieces) + B slots 0..2 (phases 0..2); retire A+slot0; frag 0
#pragma unroll
  for (int j = 0; j < 4; ++j) stageA1(0, j, 0);
  __builtin_amdgcn_sched_barrier(0);
  stageB(0, 0, 0);
  stageB(1, 1, 0);
  stageB(2, 2, 0);
  waitbar(4);
  readfrag(0, 0, 0, 0, 0);
  __builtin_amdgcn_sched_barrier(0);

#pragma unroll 1
  for (int kp = 0; kp < 3; ++kp) {  // chunks 0..5 (two per iteration)
#pragma unroll
    for (int u = 0; u < 18; ++u) body(u, 2 * kp, true);
  }
#pragma unroll
  for (int u = 0; u < 9; ++u) body(u, 6, true);   // chunk 6 (stages A for chunk 7)
#pragma unroll
  for (int u = 0; u < 9; ++u) body7(u);           // chunk 7 drain

  // ---- cross-kg reduction via LDS (over Bs_, exactly 64 KB) ----
  float* red = reinterpret_cast<float*>(&Bs_[0][0]);
  __syncthreads();
  if (kg == 1) {
#pragma unroll
    for (int n = 0; n < 4; ++n)
#pragma unroll
      for (int m = 0; m < 4; ++m)
        *reinterpret_cast<f32x4*>(red + (n * 4 + m) * 1024 + (wv & 3) * 256 + l * 4) =
            acc[n][m];
  }
  __syncthreads();
  if (kg == 0) {
    const int pixbase = ((bm & 7) << 7) + (wr << 6) + (l & 15);
    const int cob = (bn << 7) + (wc << 6) + ((l >> 4) << 2);
    float* ob = out + ((size_t)bb << 19);
    const float* drow = dmod + bb * 512;
#pragma unroll
    for (int n = 0; n < 4; ++n) {
#pragma unroll
      for (int m = 0; m < 4; ++m)
        acc[n][m] += *reinterpret_cast<const f32x4*>(red + (n * 4 + m) * 1024 + wv * 256 + l * 4);
#pragma unroll
      for (int jj = 0; jj < 4; ++jj) {
        const int co = cob + (n << 4) + jj;
        const float dv = drow[co];
        float* orow = ob + ((unsigned)co << 10) + pixbase;
#pragma unroll
        for (int m = 0; m < 4; ++m) orow[m << 4] = acc[n][m][jj] * dv;
      }
    }
  }
}

extern "C" void kernel_launch(void* const* d_in, const int* in_sizes, int n_in,
                              void* d_out, int out_size, void* d_ws, size_t ws_size,
                              hipStream_t stream) {
  (void)in_sizes; (void)n_in; (void)out_size; (void)ws_size;
  const float* x = (const float*)d_in[0];       // [8,512,32,32]
  const float* y = (const float*)d_in[1];       // [8,512]
  const float* w = (const float*)d_in[2];       // [512,512,3,3]
  const float* mw = (const float*)d_in[3];      // [512,512]
  const float* bias = (const float*)d_in[4];    // [512]
  float* out = (float*)d_out;                   // [8,512,32,32]

  char* ws = (char*)d_ws;
  float* s = (float*)(ws + 0);                  // 16 KB
  float* dmod = (float*)(ws + 16384);           // 16 KB
  float* wsq = (float*)(ws + 32768);            // 1 MB
  __hip_bfloat16* wt = (__hip_bfloat16*)(ws + 1081344);    // 9*512*512*2 = 4.5 MB
  __hip_bfloat16* xsp = (__hip_bfloat16*)(ws + 5799936);   // 8*34*34*512*2 = 9.03 MB

  prep_kernel<<<1416, 256, 0, stream>>>(w, y, mw, bias, wt, wsq, s, xsp);
  xsdem_kernel<<<2176, 256, 0, stream>>>(x, s, wsq, xsp, dmod);
  conv_kernel<<<256, 512, 0, stream>>>(xsp, wt, dmod, out);
}

// Round 11
// 61.347 us; speedup vs baseline: 1.1636x; 1.0486x over previous
//
#include <hip/hip_runtime.h>
#include <hip/hip_bf16.h>

typedef float f32x4 __attribute__((ext_vector_type(4)));
typedef short bf16x8 __attribute__((ext_vector_type(8)));

#define LRELU_SLOPE 0.2f
#define SQRT2F 1.4142135623730951f
#define MODSCALE 0.044194173824159216f  // 512^-0.5

#define GLL(SRC, DST)                                                       \
  __builtin_amdgcn_global_load_lds(                                         \
      (const __attribute__((address_space(1))) unsigned int*)(SRC),         \
      (__attribute__((address_space(3))) unsigned int*)(DST), 16, 0, 0)

// ---------- kernel 1: fused prep: wprep (blocks 0..1023) + style (1024..1151)
//            + xsp border zero (1152..1415) ----------
__global__ __launch_bounds__(256) void prep_kernel(const float* __restrict__ w,
                                                   const float* __restrict__ y,
                                                   const float* __restrict__ mw,
                                                   const float* __restrict__ bias,
                                                   __hip_bfloat16* __restrict__ wt,
                                                   float* __restrict__ wsq,
                                                   float* __restrict__ s,
                                                   __hip_bfloat16* __restrict__ xsp) {
  const int bid = blockIdx.x;
  const int tid = threadIdx.x;
  if (bid < 1024) {  // ---- weight prep: wt[t][co][ci] bf16 + wsq[co][ci] ----
    int idx = bid * 256 + tid;  // co*512+ci
    const float* p = w + (size_t)idx * 9;
    float v[9];
    float sq = 0.f;
#pragma unroll
    for (int t = 0; t < 9; ++t) {
      v[t] = p[t];
      sq += v[t] * v[t];
    }
    wsq[idx] = sq;
#pragma unroll
    for (int t = 0; t < 9; ++t) wt[t * 262144 + idx] = __float2bfloat16(v[t]);
  } else if (bid < 1152) {  // ---- style: one ci per wave ----
    int l = tid & 63;
    int ci = (bid - 1024) * 4 + (tid >> 6);
    const float4* mwr = reinterpret_cast<const float4*>(mw + ci * 512);
    float4 m0 = mwr[2 * l], m1 = mwr[2 * l + 1];
    float acc[8];
#pragma unroll
    for (int b = 0; b < 8; ++b) {
      const float4* yr = reinterpret_cast<const float4*>(y + b * 512);
      float4 y0 = yr[2 * l], y1 = yr[2 * l + 1];
      acc[b] = m0.x * y0.x + m0.y * y0.y + m0.z * y0.z + m0.w * y0.w +
               m1.x * y1.x + m1.y * y1.y + m1.z * y1.z + m1.w * y1.w;
    }
#pragma unroll
    for (int off = 32; off > 0; off >>= 1) {
#pragma unroll
      for (int b = 0; b < 8; ++b) acc[b] += __shfl_xor(acc[b], off, 64);
    }
    if (l < 8) {
      float v = acc[l] * MODSCALE + bias[ci];
      v = v > 0.f ? v : LRELU_SLOPE * v;
      s[l * 512 + ci] = v * SQRT2F;
    }
  } else {  // ---- zero the 1-px halo border of xsp (interior written by xs) ----
    int i = (bid - 1152) * 256 + tid;  // 264*256 = 67584 = 8 * 132 * 64
    int b = i / 8448;
    int r = i - b * 8448;
    int pos = r >> 6;
    int cj = (r & 63) << 3;
    int hr, hc;
    if (pos < 34) { hr = 0; hc = pos; }
    else if (pos < 68) { hr = 33; hc = pos - 34; }
    else if (pos < 100) { hr = pos - 67; hc = 0; }
    else { hr = pos - 99; hc = 33; }
    unsigned off = (unsigned)((b * 34 + hr) * 34 + hc) * 512 + cj;
    int4 z = {0, 0, 0, 0};
    *reinterpret_cast<int4*>(xsp + off) = z;
  }
}

// ---------- kernel 2: fused xs (blocks 0..2047) + demod (2048..2175) ----------
__global__ __launch_bounds__(256) void xsdem_kernel(const float* __restrict__ x,
                                                    const float* __restrict__ s,
                                                    const float* __restrict__ wsq,
                                                    __hip_bfloat16* __restrict__ xsp,
                                                    float* __restrict__ d) {
  const int bid = blockIdx.x;
  const int tid = threadIdx.x;
  if (bid < 2048) {  // ---- xs: NCHW f32 -> padded NHWC bf16, x * s ----
    int cc = bid & 7;
    int h = (bid >> 3) & 31;
    int b = bid >> 8;
    __shared__ __hip_bfloat16 tile[32][72];
    int cil = tid >> 2;
    int w0 = (tid & 3) * 8;
    int ci = cc * 64 + cil;
    const float* xp = x + (((size_t)(b * 512 + ci) * 32 + h) << 5) + w0;
    float sv = s[b * 512 + ci];
    float4 a0 = *reinterpret_cast<const float4*>(xp);
    float4 a1 = *reinterpret_cast<const float4*>(xp + 4);
    tile[w0 + 0][cil] = __float2bfloat16(a0.x * sv);
    tile[w0 + 1][cil] = __float2bfloat16(a0.y * sv);
    tile[w0 + 2][cil] = __float2bfloat16(a0.z * sv);
    tile[w0 + 3][cil] = __float2bfloat16(a0.w * sv);
    tile[w0 + 4][cil] = __float2bfloat16(a1.x * sv);
    tile[w0 + 5][cil] = __float2bfloat16(a1.y * sv);
    tile[w0 + 6][cil] = __float2bfloat16(a1.z * sv);
    tile[w0 + 7][cil] = __float2bfloat16(a1.w * sv);
    __syncthreads();
    int wloc = tid >> 3;
    int cj = (tid & 7) * 8;
    int4 v = *reinterpret_cast<const int4*>(&tile[wloc][cj]);
    unsigned off = (unsigned)((b * 34 + h + 1) * 34 + (wloc + 1)) * 512 + cc * 64 + cj;
    *reinterpret_cast<int4*>(xsp + off) = v;
  } else {  // ---- demod: one co per wave ----
    int l = tid & 63;
    int co = (bid - 2048) * 4 + (tid >> 6);
    const float4* qr = reinterpret_cast<const float4*>(wsq + co * 512);
    float4 q0 = qr[2 * l], q1 = qr[2 * l + 1];
    float acc[8];
#pragma unroll
    for (int b = 0; b < 8; ++b) {
      const float4* sr = reinterpret_cast<const float4*>(s + b * 512);
      float4 s0 = sr[2 * l], s1 = sr[2 * l + 1];
      acc[b] = q0.x * s0.x * s0.x + q0.y * s0.y * s0.y + q0.z * s0.z * s0.z +
               q0.w * s0.w * s0.w + q1.x * s1.x * s1.x + q1.y * s1.y * s1.y +
               q1.z * s1.z * s1.z + q1.w * s1.w * s1.w;
    }
#pragma unroll
    for (int off = 32; off > 0; off >>= 1) {
#pragma unroll
      for (int b = 0; b < 8; ++b) acc[b] += __shfl_xor(acc[b], off, 64);
    }
    if (l < 8) d[l * 512 + co] = rsqrtf(acc[l] + 1e-8f);
  }
}

// ---------- kernel 3: conv — halo implicit GEMM, 8 waves, K-split,
//   3-tap windows (1 barrier per window), per-wave tap ROTATION (start = wv%3),
//   register read-ahead (reads of next tap issued before current MFMA cluster) ----------
__global__ __launch_bounds__(512, 2) void conv_kernel(const __hip_bfloat16* __restrict__ xsp,
                                                      const __hip_bfloat16* __restrict__ wt,
                                                      const float* __restrict__ dmod,
                                                      float* __restrict__ out) {
  __shared__ __hip_bfloat16 As_[2][224 * 64];      // 2 x 28 KB (204 halo rows used)
  __shared__ __hip_bfloat16 Bs_[2][3 * 128 * 64];  // 2 super-slots x 48 KB
  const int bid = blockIdx.x;  // 256 blocks
  const int xcd = bid & 7, slot0 = bid >> 3;       // XCD-aware remap
  const int bm = xcd * 8 + (slot0 >> 2);
  const int bn = slot0 & 3;
  const int tid = threadIdx.x;
  const int wv = tid >> 6;
  const int l = tid & 63;
  const int kg = wv >> 2;          // K-group (owns 32 of 64 ci per chunk)
  const int wr = (wv >> 1) & 1, wc = wv & 1;
  const int bb = bm >> 3;          // batch
  const int h0 = (bm & 7) << 2;    // first output image row of tile
  const int start = wv % 3;        // per-wave tap rotation within a window
  const int p1r = start == 2 ? 0 : start + 1;
  const int p2r = 3 - start - p1r;

  const int swz = (((l & 7) ^ (l >> 3)) << 3);  // staging pre-swizzle (row&7 == l>>3)
  unsigned boff[2];
#pragma unroll
  for (int j = 0; j < 2; ++j) {
    int row = ((j * 8 + wv) << 3) + (l >> 3);
    boff[j] = (unsigned)((bn << 7) + row) * 512 + swz;
  }
  unsigned ahoff[4];
  int adst[4];
#pragma unroll
  for (int j = 0; j < 4; ++j) {
    int rb = j < 3 ? j * 64 + wv * 8 : 192 + (wv & 3) * 8;  // j=3: wave pairs duplicate
    int r = rb + (l >> 3);
    int rc = r > 203 ? 203 : r;
    int hr = rc / 34, hc = rc - hr * 34;
    ahoff[j] = (unsigned)((bb * 34 + h0 + hr) * 34 + hc) * 512 + (((l & 7) ^ (r & 7)) << 3);
    adst[j] = rb;
  }
  int pb[4];
#pragma unroll
  for (int m = 0; m < 4; ++m)
    pb[m] = ((wr << 1) + (m >> 1)) * 34 + ((m & 1) << 4) + (l & 15);

  f32x4 acc[4][4];
#pragma unroll
  for (int n = 0; n < 4; ++n)
#pragma unroll
    for (int m = 0; m < 4; ++m) acc[n][m] = (f32x4)0.f;

  bf16x8 fa[2][4], fb[2][4];  // double-banked fragments (static bank indices)

  auto stageB = [&](__hip_bfloat16* Bn, int t, int k0c) {
    const __hip_bfloat16* src = wt + t * 262144 + k0c * 64;
#pragma unroll
    for (int j = 0; j < 2; ++j)
      GLL(src + boff[j], Bn + ((j * 8 + wv) << 9));
  };
  auto stageA1 = [&](__hip_bfloat16* An, int j, int kn) {
    GLL(xsp + ahoff[j] + kn * 64, An + (adst[j] << 6));
  };
  auto readfrag = [&](int bk, const __hip_bfloat16* Aq, const __hip_bfloat16* Bq,
                      int dh, int dw) {
    const int cb = (kg << 2) + (l >> 4);
#pragma unroll
    for (int m = 0; m < 4; ++m) {
      int p = pb[m] + dh * 34 + dw;
      fa[bk][m] = *reinterpret_cast<const bf16x8*>(Aq + p * 64 + ((cb ^ (p & 7)) << 3));
    }
#pragma unroll
    for (int n = 0; n < 4; ++n) {
      int row = (wc << 6) + (n << 4) + (l & 15);
      fb[bk][n] = *reinterpret_cast<const bf16x8*>(Bq + row * 64 + ((cb ^ (l & 7)) << 3));
    }
  };
  auto mfmacl = [&](int bk) {
    __builtin_amdgcn_s_setprio(1);
#pragma unroll
    for (int n = 0; n < 4; ++n)
#pragma unroll
      for (int m = 0; m < 4; ++m)
        acc[n][m] = __builtin_amdgcn_mfma_f32_16x16x32_bf16(fb[bk][n], fa[bk][m], acc[n][m], 0, 0, 0);
    __builtin_amdgcn_s_setprio(0);
  };

#define SB0 __builtin_amdgcn_sched_barrier(0)
#define WAITBAR0                                            \
  asm volatile("s_waitcnt vmcnt(0)" ::: "memory");          \
  __builtin_amdgcn_s_barrier();                             \
  SB0

  // prologue: A halo (chunk 0) + B super-slot 0 (taps 0..2)
#pragma unroll
  for (int j = 0; j < 4; ++j) stageA1(&As_[0][0], j, 0);
  SB0;
  stageB(&Bs_[0][0] + 0 * 8192, 0, 0);
  stageB(&Bs_[0][0] + 1 * 8192, 1, 0);
  stageB(&Bs_[0][0] + 2 * 8192, 2, 0);

#pragma unroll 1
  for (int k0 = 0; k0 < 8; ++k0) {
    const __hip_bfloat16* Aq = &As_[k0 & 1][0];
    __hip_bfloat16* An = &As_[(k0 + 1) & 1][0];
#pragma unroll
    for (int dh = 0; dh < 3; ++dh) {
      __hip_bfloat16* Br = &Bs_[(k0 + dh) & 1][0];       // published this window
      __hip_bfloat16* Bo = &Bs_[((k0 + dh) & 1) ^ 1][0]; // staging target
      WAITBAR0;
      if (!(k0 == 7 && dh == 2)) {  // stage next window's 3 B slices
        const int tb = dh < 2 ? (dh + 1) * 3 : 0;
        const int kc = dh < 2 ? k0 : k0 + 1;
        stageB(Bo + 0 * 8192, tb + 0, kc);
        stageB(Bo + 1 * 8192, tb + 1, kc);
        stageB(Bo + 2 * 8192, tb + 2, kc);
      }
      if (k0 < 7) {  // A halo for chunk k0+1, split over windows 0/1
        if (dh == 0) { stageA1(An, 0, k0 + 1); stageA1(An, 1, k0 + 1); }
        else if (dh == 1) { stageA1(An, 2, k0 + 1); stageA1(An, 3, k0 + 1); }
      }
      SB0;
      // rotated taps p0,p1,p2 (per-wave); read-ahead one tap
      readfrag(0, Aq, Br + start * 8192, dh, start);
      SB0;
      readfrag(1, Aq, Br + p1r * 8192, dh, p1r);
      SB0;
      mfmacl(0);            // tap p0 (reads of p1 in flight under it)
      SB0;
      readfrag(0, Aq, Br + p2r * 8192, dh, p2r);
      SB0;
      mfmacl(1);            // tap p1 (reads of p2 in flight under it)
      SB0;
      mfmacl(0);            // tap p2
    }
  }
#undef WAITBAR0
#undef SB0

  // ---- cross-kg reduction via LDS (over Bs_, 96 KB >= 64 KB) ----
  float* red = reinterpret_cast<float*>(&Bs_[0][0]);
  __syncthreads();
  if (kg == 1) {
#pragma unroll
    for (int n = 0; n < 4; ++n)
#pragma unroll
      for (int m = 0; m < 4; ++m)
        *reinterpret_cast<f32x4*>(red + (n * 4 + m) * 1024 + (wv & 3) * 256 + l * 4) =
            acc[n][m];
  }
  __syncthreads();
  if (kg == 0) {
    const int pixbase = ((bm & 7) << 7) + (wr << 6) + (l & 15);
    const int cob = (bn << 7) + (wc << 6) + ((l >> 4) << 2);
    float* ob = out + ((size_t)bb << 19);
    const float* drow = dmod + bb * 512;
#pragma unroll
    for (int n = 0; n < 4; ++n) {
#pragma unroll
      for (int m = 0; m < 4; ++m)
        acc[n][m] += *reinterpret_cast<const f32x4*>(red + (n * 4 + m) * 1024 + wv * 256 + l * 4);
#pragma unroll
      for (int jj = 0; jj < 4; ++jj) {
        const int co = cob + (n << 4) + jj;
        const float dv = drow[co];
        float* orow = ob + ((unsigned)co << 10) + pixbase;
#pragma unroll
        for (int m = 0; m < 4; ++m) orow[m << 4] = acc[n][m][jj] * dv;
      }
    }
  }
}

extern "C" void kernel_launch(void* const* d_in, const int* in_sizes, int n_in,
                              void* d_out, int out_size, void* d_ws, size_t ws_size,
                              hipStream_t stream) {
  (void)in_sizes; (void)n_in; (void)out_size; (void)ws_size;
  const float* x = (const float*)d_in[0];       // [8,512,32,32]
  const float* y = (const float*)d_in[1];       // [8,512]
  const float* w = (const float*)d_in[2];       // [512,512,3,3]
  const float* mw = (const float*)d_in[3];      // [512,512]
  const float* bias = (const float*)d_in[4];    // [512]
  float* out = (float*)d_out;                   // [8,512,32,32]

  char* ws = (char*)d_ws;
  float* s = (float*)(ws + 0);                  // 16 KB
  float* dmod = (float*)(ws + 16384);           // 16 KB
  float* wsq = (float*)(ws + 32768);            // 1 MB
  __hip_bfloat16* wt = (__hip_bfloat16*)(ws + 1081344);    // 9*512*512*2 = 4.5 MB
  __hip_bfloat16* xsp = (__hip_bfloat16*)(ws + 5799936);   // 8*34*34*512*2 = 9.03 MB

  prep_kernel<<<1416, 256, 0, stream>>>(w, y, mw, bias, wt, wsq, s, xsp);
  xsdem_kernel<<<2176, 256, 0, stream>>>(x, s, wsq, xsp, dmod);
  conv_kernel<<<256, 512, 0, stream>>>(xsp, wt, dmod, out);
}

// Round 12
// 59.871 us; speedup vs baseline: 1.1923x; 1.0246x over previous
//
#include <hip/hip_runtime.h>
#include <hip/hip_bf16.h>

typedef float f32x4 __attribute__((ext_vector_type(4)));
typedef short bf16x8 __attribute__((ext_vector_type(8)));

#define LRELU_SLOPE 0.2f
#define SQRT2F 1.4142135623730951f
#define MODSCALE 0.044194173824159216f  // 512^-0.5

#define GLL(SRC, DST)                                                       \
  __builtin_amdgcn_global_load_lds(                                         \
      (const __attribute__((address_space(1))) unsigned int*)(SRC),         \
      (__attribute__((address_space(3))) unsigned int*)(DST), 16, 0, 0)

// ---------- kernel 1: fused prep: wprep (blocks 0..1023) + style (1024..1151)
//            + xsp border zero (1152..1415) ----------
// wt2 layout: [t][kchunk c(8)][kg(2)][co(512)][ci32] bf16 — slab = 32 KB, a B-fragment
// (16 co x 32 ci) is 1 KB contiguous => fully coalesced global->VGPR MFMA operand.
__global__ __launch_bounds__(256) void prep_kernel(const float* __restrict__ w,
                                                   const float* __restrict__ y,
                                                   const float* __restrict__ mw,
                                                   const float* __restrict__ bias,
                                                   __hip_bfloat16* __restrict__ wt2,
                                                   float* __restrict__ wsq,
                                                   float* __restrict__ s,
                                                   __hip_bfloat16* __restrict__ xsp) {
  const int bid = blockIdx.x;
  const int tid = threadIdx.x;
  if (bid < 1024) {  // ---- weight prep ----
    int idx = bid * 256 + tid;  // co*512+ci
    int co = idx >> 9, ci = idx & 511;
    const float* p = w + (size_t)idx * 9;
    float v[9];
    float sq = 0.f;
#pragma unroll
    for (int t = 0; t < 9; ++t) {
      v[t] = p[t];
      sq += v[t] * v[t];
    }
    wsq[idx] = sq;
    int slabbase = ((ci >> 6) * 2 + ((ci >> 5) & 1)) * 16384 + co * 32 + (ci & 31);
#pragma unroll
    for (int t = 0; t < 9; ++t)
      wt2[t * 262144 + slabbase] = __float2bfloat16(v[t]);
  } else if (bid < 1152) {  // ---- style: one ci per wave ----
    int l = tid & 63;
    int ci = (bid - 1024) * 4 + (tid >> 6);
    const float4* mwr = reinterpret_cast<const float4*>(mw + ci * 512);
    float4 m0 = mwr[2 * l], m1 = mwr[2 * l + 1];
    float acc[8];
#pragma unroll
    for (int b = 0; b < 8; ++b) {
      const float4* yr = reinterpret_cast<const float4*>(y + b * 512);
      float4 y0 = yr[2 * l], y1 = yr[2 * l + 1];
      acc[b] = m0.x * y0.x + m0.y * y0.y + m0.z * y0.z + m0.w * y0.w +
               m1.x * y1.x + m1.y * y1.y + m1.z * y1.z + m1.w * y1.w;
    }
#pragma unroll
    for (int off = 32; off > 0; off >>= 1) {
#pragma unroll
      for (int b = 0; b < 8; ++b) acc[b] += __shfl_xor(acc[b], off, 64);
    }
    if (l < 8) {
      float v = acc[l] * MODSCALE + bias[ci];
      v = v > 0.f ? v : LRELU_SLOPE * v;
      s[l * 512 + ci] = v * SQRT2F;
    }
  } else {  // ---- zero the 1-px halo border of xsp ----
    int i = (bid - 1152) * 256 + tid;  // 264*256 = 8 * 132 * 64
    int b = i / 8448;
    int r = i - b * 8448;
    int pos = r >> 6;
    int cj = (r & 63) << 3;
    int hr, hc;
    if (pos < 34) { hr = 0; hc = pos; }
    else if (pos < 68) { hr = 33; hc = pos - 34; }
    else if (pos < 100) { hr = pos - 67; hc = 0; }
    else { hr = pos - 99; hc = 33; }
    unsigned off = (unsigned)((b * 34 + hr) * 34 + hc) * 512 + cj;
    int4 z = {0, 0, 0, 0};
    *reinterpret_cast<int4*>(xsp + off) = z;
  }
}

// ---------- kernel 2: fused xs (blocks 0..2047) + demod (2048..2175) ----------
__global__ __launch_bounds__(256) void xsdem_kernel(const float* __restrict__ x,
                                                    const float* __restrict__ s,
                                                    const float* __restrict__ wsq,
                                                    __hip_bfloat16* __restrict__ xsp,
                                                    float* __restrict__ d) {
  const int bid = blockIdx.x;
  const int tid = threadIdx.x;
  if (bid < 2048) {  // ---- xs: NCHW f32 -> padded NHWC bf16, x * s ----
    int cc = bid & 7;
    int h = (bid >> 3) & 31;
    int b = bid >> 8;
    __shared__ __hip_bfloat16 tile[32][72];
    int cil = tid >> 2;
    int w0 = (tid & 3) * 8;
    int ci = cc * 64 + cil;
    const float* xp = x + (((size_t)(b * 512 + ci) * 32 + h) << 5) + w0;
    float sv = s[b * 512 + ci];
    float4 a0 = *reinterpret_cast<const float4*>(xp);
    float4 a1 = *reinterpret_cast<const float4*>(xp + 4);
    tile[w0 + 0][cil] = __float2bfloat16(a0.x * sv);
    tile[w0 + 1][cil] = __float2bfloat16(a0.y * sv);
    tile[w0 + 2][cil] = __float2bfloat16(a0.z * sv);
    tile[w0 + 3][cil] = __float2bfloat16(a0.w * sv);
    tile[w0 + 4][cil] = __float2bfloat16(a1.x * sv);
    tile[w0 + 5][cil] = __float2bfloat16(a1.y * sv);
    tile[w0 + 6][cil] = __float2bfloat16(a1.z * sv);
    tile[w0 + 7][cil] = __float2bfloat16(a1.w * sv);
    __syncthreads();
    int wloc = tid >> 3;
    int cj = (tid & 7) * 8;
    int4 v = *reinterpret_cast<const int4*>(&tile[wloc][cj]);
    unsigned off = (unsigned)((b * 34 + h + 1) * 34 + (wloc + 1)) * 512 + cc * 64 + cj;
    *reinterpret_cast<int4*>(xsp + off) = v;
  } else {  // ---- demod ----
    int l = tid & 63;
    int co = (bid - 2048) * 4 + (tid >> 6);
    const float4* qr = reinterpret_cast<const float4*>(wsq + co * 512);
    float4 q0 = qr[2 * l], q1 = qr[2 * l + 1];
    float acc[8];
#pragma unroll
    for (int b = 0; b < 8; ++b) {
      const float4* sr = reinterpret_cast<const float4*>(s + b * 512);
      float4 s0 = sr[2 * l], s1 = sr[2 * l + 1];
      acc[b] = q0.x * s0.x * s0.x + q0.y * s0.y * s0.y + q0.z * s0.z * s0.z +
               q0.w * s0.w * s0.w + q1.x * s1.x * s1.x + q1.y * s1.y * s1.y +
               q1.z * s1.z * s1.z + q1.w * s1.w * s1.w;
    }
#pragma unroll
    for (int off = 32; off > 0; off >>= 1) {
#pragma unroll
      for (int b = 0; b < 8; ++b) acc[b] += __shfl_xor(acc[b], off, 64);
    }
    if (l < 8) d[l * 512 + co] = rsqrtf(acc[l] + 1e-8f);
  }
}

// ---------- kernel 3: conv — halo implicit GEMM, 8 waves, K-split,
//   A via LDS halo (only LDS consumer), B-fragments DIRECT global->register from L2
//   (coalesced 1 KB per load), double-banked 1 tap ahead. 1 barrier per K-chunk. ----------
__global__ __launch_bounds__(512, 2) void conv_kernel(const __hip_bfloat16* __restrict__ xsp,
                                                      const __hip_bfloat16* __restrict__ wt2,
                                                      const float* __restrict__ dmod,
                                                      float* __restrict__ out) {
  __shared__ __hip_bfloat16 As_[2][224 * 64];  // 2 x 28 KB (204 halo rows used)
  __shared__ float red[16384];                 // 64 KB cross-kg reduction buffer
  const int bid = blockIdx.x;  // 256 blocks
  const int xcd = bid & 7, slot0 = bid >> 3;   // XCD-aware remap
  const int bm = xcd * 8 + (slot0 >> 2);
  const int bn = slot0 & 3;
  const int tid = threadIdx.x;
  const int wv = tid >> 6;
  const int l = tid & 63;
  const int kg = wv >> 2;          // K-group (owns 32 of 64 ci per chunk)
  const int wr = (wv >> 1) & 1, wc = wv & 1;
  const int bb = bm >> 3;          // batch
  const int h0 = (bm & 7) << 2;    // first output image row of tile

  // ---- A staging offsets (pre-swizzled global source), as r11 ----
  unsigned ahoff[4];
  int adst[4];
#pragma unroll
  for (int j = 0; j < 4; ++j) {
    int rb = j < 3 ? j * 64 + wv * 8 : 192 + (wv & 3) * 8;
    int r = rb + (l >> 3);
    int rc = r > 203 ? 203 : r;
    int hr = rc / 34, hc = rc - hr * 34;
    ahoff[j] = (unsigned)((bb * 34 + h0 + hr) * 34 + hc) * 512 + (((l & 7) ^ (r & 7)) << 3);
    adst[j] = rb;
  }
  int pb[4];
#pragma unroll
  for (int m = 0; m < 4; ++m)
    pb[m] = ((wr << 1) + (m >> 1)) * 34 + ((m & 1) << 4) + (l & 15);

  // ---- B direct-load lane base: frag = [16 co][32 ci] = 1 KB contiguous ----
  const char* wtb = reinterpret_cast<const char*>(wt2);
  const unsigned nbase = (unsigned)(bn << 13) + (wc << 12) + ((l & 15) << 6) + ((l >> 4) << 4);

  f32x4 acc[4][4];
#pragma unroll
  for (int n = 0; n < 4; ++n)
#pragma unroll
    for (int m = 0; m < 4; ++m) acc[n][m] = (f32x4)0.f;

  bf16x8 fbk[2][4];  // double-banked B fragments (bank index always literal)

  auto stageA1 = [&](__hip_bfloat16* An, int j, int kn) {
    GLL(xsp + ahoff[j] + kn * 64, An + (adst[j] << 6));
  };
  auto loadB = [&](int bank, int t, int c) {
    const char* base = wtb + (size_t)(((t * 8 + c) * 2 + kg) << 15) + nbase;
#pragma unroll
    for (int n = 0; n < 4; ++n)
      fbk[bank][n] = *reinterpret_cast<const bf16x8*>(base + (n << 10));
  };
  auto doTap = [&](int bank, const __hip_bfloat16* Aq, int dh, int dw) {
    const int cb = (kg << 2) + (l >> 4);
    bf16x8 af[4];
#pragma unroll
    for (int m = 0; m < 4; ++m) {
      int p = pb[m] + dh * 34 + dw;
      af[m] = *reinterpret_cast<const bf16x8*>(Aq + p * 64 + ((cb ^ (p & 7)) << 3));
    }
    __builtin_amdgcn_s_setprio(1);
#pragma unroll
    for (int n = 0; n < 4; ++n)
#pragma unroll
      for (int m = 0; m < 4; ++m)
        acc[n][m] = __builtin_amdgcn_mfma_f32_16x16x32_bf16(fbk[bank][n], af[m], acc[n][m], 0, 0, 0);
    __builtin_amdgcn_s_setprio(0);
  };
  // chunk c: B(t) lives in bank (P+t)&1 (P = c&1, literal via call sites).
  // Phase t: load B(t+1) [t=8: tap0 of chunk c+1], stage A(c+1) at t==0, MFMA tap t.
  auto chunkBody = [&](int c, int P, bool stA, bool last) {
    const __hip_bfloat16* Aq = &As_[P][0];
    __hip_bfloat16* An = &As_[P ^ 1][0];
#pragma unroll
    for (int t = 0; t < 9; ++t) {
      if (!last || t < 8) loadB((P + t + 1) & 1, (t + 1) % 9, t < 8 ? c : c + 1);
      if (stA && t == 0) {
        stageA1(An, 0, c + 1); stageA1(An, 1, c + 1);
        stageA1(An, 2, c + 1); stageA1(An, 3, c + 1);
        __builtin_amdgcn_sched_barrier(0);  // pin: A-stage before all later B loads
      }
      doTap((P + t) & 1, Aq, t / 3, t % 3);
    }
    if (!last) {
      // queue tail: [..., As(c+1)x4 (long retired), B(0,c+1)x4] -> vmcnt(4) retires As
      asm volatile("s_waitcnt vmcnt(4)" ::: "memory");
      __builtin_amdgcn_s_barrier();
      __builtin_amdgcn_sched_barrier(0);
    }
  };

  // prologue: A halo chunk 0, then B(0,0) into bank 0
#pragma unroll
  for (int j = 0; j < 4; ++j) stageA1(&As_[0][0], j, 0);
  __builtin_amdgcn_sched_barrier(0);  // A-stage precedes B loads in VMEM queue
  loadB(0, 0, 0);
  asm volatile("s_waitcnt vmcnt(4)" ::: "memory");  // A halo staged (B may fly)
  __builtin_amdgcn_s_barrier();
  __builtin_amdgcn_sched_barrier(0);

#pragma unroll 1
  for (int kp = 0; kp < 3; ++kp) {  // chunks 0..5, parity compile-time
    chunkBody(2 * kp, 0, true, false);
    chunkBody(2 * kp + 1, 1, true, false);
  }
  chunkBody(6, 0, true, false);   // stages A halo for chunk 7
  chunkBody(7, 1, false, true);   // drain

  // ---- cross-kg reduction via dedicated LDS buffer ----
  __syncthreads();
  if (kg == 1) {
#pragma unroll
    for (int n = 0; n < 4; ++n)
#pragma unroll
      for (int m = 0; m < 4; ++m)
        *reinterpret_cast<f32x4*>(red + (n * 4 + m) * 1024 + (wv & 3) * 256 + l * 4) =
            acc[n][m];
  }
  __syncthreads();
  if (kg == 0) {
    const int pixbase = ((bm & 7) << 7) + (wr << 6) + (l & 15);
    const int cob = (bn << 7) + (wc << 6) + ((l >> 4) << 2);
    float* ob = out + ((size_t)bb << 19);
    const float* drow = dmod + bb * 512;
#pragma unroll
    for (int n = 0; n < 4; ++n) {
#pragma unroll
      for (int m = 0; m < 4; ++m)
        acc[n][m] += *reinterpret_cast<const f32x4*>(red + (n * 4 + m) * 1024 + wv * 256 + l * 4);
#pragma unroll
      for (int jj = 0; jj < 4; ++jj) {
        const int co = cob + (n << 4) + jj;
        const float dv = drow[co];
        float* orow = ob + ((unsigned)co << 10) + pixbase;
#pragma unroll
        for (int m = 0; m < 4; ++m) orow[m << 4] = acc[n][m][jj] * dv;
      }
    }
  }
}

extern "C" void kernel_launch(void* const* d_in, const int* in_sizes, int n_in,
                              void* d_out, int out_size, void* d_ws, size_t ws_size,
                              hipStream_t stream) {
  (void)in_sizes; (void)n_in; (void)out_size; (void)ws_size;
  const float* x = (const float*)d_in[0];       // [8,512,32,32]
  const float* y = (const float*)d_in[1];       // [8,512]
  const float* w = (const float*)d_in[2];       // [512,512,3,3]
  const float* mw = (const float*)d_in[3];      // [512,512]
  const float* bias = (const float*)d_in[4];    // [512]
  float* out = (float*)d_out;                   // [8,512,32,32]

  char* ws = (char*)d_ws;
  float* s = (float*)(ws + 0);                  // 16 KB
  float* dmod = (float*)(ws + 16384);           // 16 KB
  float* wsq = (float*)(ws + 32768);            // 1 MB
  __hip_bfloat16* wt2 = (__hip_bfloat16*)(ws + 1081344);   // 9*8*2*512*32*2 = 4.5 MB
  __hip_bfloat16* xsp = (__hip_bfloat16*)(ws + 5799936);   // 8*34*34*512*2 = 9.03 MB

  prep_kernel<<<1416, 256, 0, stream>>>(w, y, mw, bias, wt2, wsq, s, xsp);
  xsdem_kernel<<<2176, 256, 0, stream>>>(x, s, wsq, xsp, dmod);
  conv_kernel<<<256, 512, 0, stream>>>(xsp, wt2, dmod, out);
}